// Round 8
// baseline (246.769 us; speedup 1.0000x reference)
//
#include <hip/hip_runtime.h>

typedef _Float16 f16;
typedef _Float16 f16x8 __attribute__((ext_vector_type(8)));
typedef float    f32x4 __attribute__((ext_vector_type(4)));

// async global->LDS, 16B per lane; LDS dest = wave-uniform base + lane*16.
// Global source address is per-lane arbitrary (we exploit this for swizzling).
__device__ __forceinline__ void gld_lds16(const void* g, void* l) {
    __builtin_amdgcn_global_load_lds((__attribute__((address_space(1))) void*)g,
                                     (__attribute__((address_space(3))) void*)l,
                                     16, 0, 0);
}

// compiler-barrier-wrapped s_barrier: LDS/global ops must not migrate across.
#define BARRIER() do { asm volatile("" ::: "memory"); \
                       __builtin_amdgcn_s_barrier();  \
                       asm volatile("" ::: "memory"); } while (0)

// ---------------------------------------------------------------------------
// 8-phase 256x256xBK64 GEMM (C = A * B^T, f16 out), K = 1024 (16 K-tiles).
// 512 thr = 8 waves (2Mx4N); per-wave 128x64 output = acc[8][4] 16x16 frags.
// LDS: 2 buffers x (A 256x64 + B 256x64) f16 = 128 KiB, XOR-chunk swizzled.
// Per K-tile t (reads buf[t&1]; stages tile t+1 into buf[(t+1)&1]). 4 phases,
// 16 MFMA each; fragment reads are per-phase (peak ~10 live frags, no spill).
// vmcnt(2) at end-ph1/ph4 only: loads never drain to 0 in the main loop.
// ---------------------------------------------------------------------------
template<bool STG, int VM1, int VM4>
__device__ __forceinline__ void tile256(
    f32x4 (&acc)[8][4],
    const f16* Ak0, const f16* Ak1, const f16* Bk0, const f16* Bk1,
    const f16* gAn, const f16* gBn,   // next-tile global bases (k-adjusted)
    f16* lAn, f16* lBn,               // next-tile LDS dests (other buffer)
    int lda, int ldb)
{
    // ---- phase 1: kk0, m-frags 0-3 ----
    {
        f16x8 a[4], b[4];
        #pragma unroll
        for (int mf = 0; mf < 4; mf++) a[mf] = *(const f16x8*)(Ak0 + mf * 1024);
        #pragma unroll
        for (int nf = 0; nf < 4; nf++) b[nf] = *(const f16x8*)(Bk0 + nf * 1024);
        if (STG) {
            gld_lds16(gBn,                  lBn);
            gld_lds16(gBn + (long)64 * ldb, lBn + 4096);
        }
        BARRIER();
        __builtin_amdgcn_s_setprio(1);
        #pragma unroll
        for (int mf = 0; mf < 4; mf++)
            #pragma unroll
            for (int nf = 0; nf < 4; nf++)
                acc[mf][nf] = __builtin_amdgcn_mfma_f32_16x16x32_f16(
                    a[mf], b[nf], acc[mf][nf], 0, 0, 0);
        __builtin_amdgcn_s_setprio(0);
        if (VM1 == 2)      asm volatile("s_waitcnt vmcnt(2)" ::: "memory");
        else if (VM1 == 0) asm volatile("s_waitcnt vmcnt(0)" ::: "memory");
        BARRIER();
        // ---- phase 2: kk0, m-frags 4-7 (b still live) ----
        f16x8 a2[4];
        #pragma unroll
        for (int mf = 0; mf < 4; mf++) a2[mf] = *(const f16x8*)(Ak0 + (mf + 4) * 1024);
        if (STG) {
            gld_lds16(gBn + (long)128 * ldb, lBn + 8192);
            gld_lds16(gBn + (long)192 * ldb, lBn + 12288);
        }
        BARRIER();
        __builtin_amdgcn_s_setprio(1);
        #pragma unroll
        for (int mf = 0; mf < 4; mf++)
            #pragma unroll
            for (int nf = 0; nf < 4; nf++)
                acc[mf + 4][nf] = __builtin_amdgcn_mfma_f32_16x16x32_f16(
                    a2[mf], b[nf], acc[mf + 4][nf], 0, 0, 0);
        __builtin_amdgcn_s_setprio(0);
        BARRIER();
    }
    // ---- phase 3: kk1, m-frags 0-3 ----
    {
        f16x8 a[4], b[4];
        #pragma unroll
        for (int mf = 0; mf < 4; mf++) a[mf] = *(const f16x8*)(Ak1 + mf * 1024);
        #pragma unroll
        for (int nf = 0; nf < 4; nf++) b[nf] = *(const f16x8*)(Bk1 + nf * 1024);
        if (STG) {
            gld_lds16(gAn,                   lAn);
            gld_lds16(gAn + (long)128 * lda, lAn + 8192);
        }
        BARRIER();
        __builtin_amdgcn_s_setprio(1);
        #pragma unroll
        for (int mf = 0; mf < 4; mf++)
            #pragma unroll
            for (int nf = 0; nf < 4; nf++)
                acc[mf][nf] = __builtin_amdgcn_mfma_f32_16x16x32_f16(
                    a[mf], b[nf], acc[mf][nf], 0, 0, 0);
        __builtin_amdgcn_s_setprio(0);
        BARRIER();
        // ---- phase 4: kk1, m-frags 4-7 ----
        f16x8 a2[4];
        #pragma unroll
        for (int mf = 0; mf < 4; mf++) a2[mf] = *(const f16x8*)(Ak1 + (mf + 4) * 1024);
        if (STG) {
            gld_lds16(gAn + (long)64 * lda,  lAn + 4096);
            gld_lds16(gAn + (long)192 * lda, lAn + 12288);
        }
        BARRIER();
        __builtin_amdgcn_s_setprio(1);
        #pragma unroll
        for (int mf = 0; mf < 4; mf++)
            #pragma unroll
            for (int nf = 0; nf < 4; nf++)
                acc[mf + 4][nf] = __builtin_amdgcn_mfma_f32_16x16x32_f16(
                    a2[mf], b[nf], acc[mf + 4][nf], 0, 0, 0);
        __builtin_amdgcn_s_setprio(0);
        if (VM4 == 2)      asm volatile("s_waitcnt vmcnt(2)" ::: "memory");
        else if (VM4 == 0) asm volatile("s_waitcnt vmcnt(0)" ::: "memory");
        BARRIER();
    }
}

// grid = 256 1-D blocks. XCD-chunk swizzle (T1): XCD k gets 32 consecutive
// logical tiles = 4 i-tiles x all 8 j-tiles, so the full B operand (4 MB)
// exactly fits that XCD's L2 and A-panels are fetched once per XCD.
__global__ void __launch_bounds__(512, 2)
gemm256_k1024(const f16* __restrict__ A, const f16* __restrict__ B,
              f16* __restrict__ C, int lda, int ldb, int ldc)
{
    const int m  = (int)blockIdx.x;            // 0..255
    const int L  = (m & 7) * 32 + (m >> 3);    // bijective: 256 = 8*32
    const int i0 = (L >> 3) * 256;             // 32 i-tiles
    const int j0 = (L & 7) * 256;              // 8 j-tiles

    __shared__ f16 Lds[2 * 32768] __attribute__((aligned(16)));

    const int tid  = threadIdx.x;
    const int lane = tid & 63;
    const int wave = tid >> 6;
    const int wm = wave >> 2, wn = wave & 3;
    const int row16 = lane & 15, quad = lane >> 4;
    const int swz = row16 & 7;

    // per-thread LDS read bases (buf0; buf1 = +32768). chunk XOR-deswizzle:
    // LDS[row][cb] holds global chunk cb^(row&7) -> read chunk (k-chunk ^ swz).
    const int c0 = (quad ^ swz) * 8;           // kk0 chunk
    const int c1 = ((quad + 4) ^ swz) * 8;     // kk1 chunk
    const f16* A0k0 = Lds + (wm * 128 + row16) * 64 + c0;
    const f16* A0k1 = Lds + (wm * 128 + row16) * 64 + c1;
    const f16* B0k0 = Lds + 16384 + (wn * 64 + row16) * 64 + c0;
    const f16* B0k1 = Lds + 16384 + (wn * 64 + row16) * 64 + c1;

    // staging: 512 thr x 16B cover one 64-row quarter (64x64 f16) per issue.
    const int srow = tid >> 3;                       // 0..63
    const int scol = ((tid & 7) ^ (srow & 7)) * 8;   // swizzled global col
    const f16* gA = A + (long)(i0 + srow) * lda + scol;
    const f16* gB = B + (long)(j0 + srow) * ldb + scol;
    f16* lA0 = Lds + tid * 8;
    f16* lB0 = Lds + 16384 + tid * 8;
    f16* lA1 = Lds + 32768 + tid * 8;
    f16* lB1 = Lds + 32768 + 16384 + tid * 8;

    // prologue: tile 0 -> buf0, issue order = steady staging order:
    // Bq0,Bq1,Bq2,Bq3,Aq0,Aq2,Aq1,Aq3; vmcnt(2) keeps Aq1,Aq3 in flight.
    gld_lds16(gB,                   lB0);
    gld_lds16(gB + (long)64 * ldb,  lB0 + 4096);
    gld_lds16(gB + (long)128 * ldb, lB0 + 8192);
    gld_lds16(gB + (long)192 * ldb, lB0 + 12288);
    gld_lds16(gA,                   lA0);
    gld_lds16(gA + (long)128 * lda, lA0 + 8192);
    gld_lds16(gA + (long)64 * lda,  lA0 + 4096);
    gld_lds16(gA + (long)192 * lda, lA0 + 12288);

    f32x4 acc[8][4] = {};

    asm volatile("s_waitcnt vmcnt(2)" ::: "memory");
    BARRIER();

    // 16 K-tiles: 7 steady pairs (tiles 0-13) + tile 14 (last stage) + tile 15
    for (int t = 0; t < 14; t += 2) {
        tile256<true, 2, 2>(acc, A0k0, A0k1, B0k0, B0k1,
                            gA + (t + 1) * 64, gB + (t + 1) * 64,
                            lA1, lB1, lda, ldb);
        tile256<true, 2, 2>(acc, A0k0 + 32768, A0k1 + 32768,
                            B0k0 + 32768, B0k1 + 32768,
                            gA + (t + 2) * 64, gB + (t + 2) * 64,
                            lA0, lB0, lda, ldb);
    }
    tile256<true, 2, 2>(acc, A0k0, A0k1, B0k0, B0k1,
                        gA + 15 * 64, gB + 15 * 64, lA1, lB1, lda, ldb);
    tile256<false, 0, -1>(acc, A0k0 + 32768, A0k1 + 32768,
                          B0k0 + 32768, B0k1 + 32768,
                          nullptr, nullptr, nullptr, nullptr, lda, ldb);

    // epilogue: C[row][col], col = lane&15, row = quad*4 + reg
    #pragma unroll
    for (int mf = 0; mf < 8; mf++) {
        const int r0 = i0 + wm * 128 + mf * 16 + quad * 4;
        #pragma unroll
        for (int nf = 0; nf < 4; nf++) {
            const int c = j0 + wn * 64 + nf * 16 + row16;
            #pragma unroll
            for (int r = 0; r < 4; r++)
                C[(long)(r0 + r) * ldc + c] = (f16)acc[mf][nf][r];
        }
    }
}

// ---------------------------------------------------------------------------
// 128x64 GEMM body over K range [kLo, kHi), shared by vt_sc and split-K PV.
// 4 waves 2x2, each wave 64x32 out (acc[4][2]); ~48 VGPR / 24KB LDS -> 6+
// blocks/CU; cross-block overlap hides the 2-barrier drain stall.
// ATOMIC=true: epilogue accumulates into C via device-scope f32 atomicAdd
// (split-K partials; harness zeroes the output buffer before each launch).
// ---------------------------------------------------------------------------
template<typename OutT, bool ATOMIC>
__device__ __forceinline__ void gemm128_body(
    const f16* __restrict__ A, const f16* __restrict__ B, OutT* __restrict__ C,
    int lda, int ldb, int ldc, int kLo, int kHi, float scale, int i0, int j0)
{
    __shared__ f16 As[128 * 64] __attribute__((aligned(16)));
    __shared__ f16 Bs[64 * 64]  __attribute__((aligned(16)));

    const int tid  = threadIdx.x;
    const int lane = tid & 63;
    const int wave = tid >> 6;
    const int row16 = lane & 15;
    const int quad  = lane >> 4;
    const int swz   = row16 & 7;
    const int wr = (wave >> 1) * 64;   // wave row offset: 0 / 64
    const int wc = (wave & 1) * 32;    // wave col offset: 0 / 32

    const int srow = tid >> 3;                       // 0..31
    const int scol = ((tid & 7) ^ (srow & 7)) * 8;   // swizzled global col
    const f16* gA = A + (long)(i0 + srow) * lda + scol;
    const f16* gB = B + (long)(j0 + srow) * ldb + scol;
    f16* lA = As + tid * 8;   // + p*32*64
    f16* lB = Bs + tid * 8;

    f32x4 acc[4][2] = {};

    for (int k0 = kLo; k0 < kHi; k0 += 64) {
        gld_lds16(gA + k0,                  lA);
        gld_lds16(gA + k0 + (long)32 * lda, lA + 32 * 64);
        gld_lds16(gA + k0 + (long)64 * lda, lA + 64 * 64);
        gld_lds16(gA + k0 + (long)96 * lda, lA + 96 * 64);
        gld_lds16(gB + k0,                  lB);
        gld_lds16(gB + k0 + (long)32 * ldb, lB + 32 * 64);
        __syncthreads();

        #pragma unroll
        for (int kk = 0; kk < 2; kk++) {
            f16x8 af[4], bf[2];
            #pragma unroll
            for (int t = 0; t < 4; t++)
                af[t] = *(const f16x8*)(As + (wr + t * 16 + row16) * 64
                                           + (((kk * 4 + quad) ^ swz) * 8));
            #pragma unroll
            for (int t = 0; t < 2; t++)
                bf[t] = *(const f16x8*)(Bs + (wc + t * 16 + row16) * 64
                                           + (((kk * 4 + quad) ^ swz) * 8));
            #pragma unroll
            for (int mt = 0; mt < 4; mt++)
                #pragma unroll
                for (int nt = 0; nt < 2; nt++)
                    acc[mt][nt] = __builtin_amdgcn_mfma_f32_16x16x32_f16(
                        af[mt], bf[nt], acc[mt][nt], 0, 0, 0);
        }
        __syncthreads();
    }

    // epilogue: C[row][col], col = lane&15, row = quad*4 + reg
    #pragma unroll
    for (int mt = 0; mt < 4; mt++) {
        const int r0 = i0 + wr + mt * 16 + quad * 4;
        #pragma unroll
        for (int nt = 0; nt < 2; nt++) {
            const int c = j0 + wc + nt * 16 + row16;
            #pragma unroll
            for (int r = 0; r < 4; r++) {
                if (ATOMIC)
                    atomicAdd((float*)&C[(long)(r0 + r) * ldc + c],
                              acc[mt][nt][r] * scale);
                else
                    C[(long)(r0 + r) * ldc + c] = (OutT)(acc[mt][nt][r] * scale);
            }
        }
    }
}

// Merged V^T + scores dispatch: 2112 uniform-work blocks (K=1024), with
// XCD-chunk swizzles (T1) so panel-sharing blocks land on one XCD's L2:
//  blocks [0,1024): V^T = Wv x^T. Logical order i-inner/j-outer (L = j*8+i);
//    chunk 128 logical tiles per XCD -> each xh B-panel (128KB, shared by the
//    8 i-blocks) is consumed within one XCD; wvh (2MB) is L2-resident.
//  blocks [1024,2112): Sc = Q K^T / 32, lower-tri 64-wide tiles (272/batch,
//    row-band-major); chunk 136 per XCD -> Q-panels fetched once per XCD.
// Measured at the 128-engine structural floor (49.3 us vs 51 ideal, r7).
__global__ void __launch_bounds__(256)
gemm_vt_sc(const f16* __restrict__ xh, const f16* __restrict__ wvh,
           const f16* __restrict__ QKh, f16* __restrict__ Vt,
           f16* __restrict__ Sc)
{
    const int blk = (int)blockIdx.x;
    if (blk < 1024) {
        const int L = (blk & 7) * 128 + (blk >> 3);   // bijective: 1024 = 8*128
        const int j = L >> 3;                          // 0..127 (col tile)
        const int i = L & 7;                           // 0..7   (row tile)
        gemm128_body<f16, false>(wvh, xh, Vt, 1024, 1024, 8192, 0, 1024, 1.f,
                                 i * 128, j * 64);
    } else {
        const int m = blk - 1024;                      // 0..1087
        const int L = (m & 7) * 136 + (m >> 3);        // bijective: 1088 = 8*136
        const int z = L / 272;                         // batch
        const int r = L - z * 272;
        int y = 0;
        while ((y + 1) * (y + 2) <= r) y++;            // cum(y) = y(y+1); r <= 271
        const int x = r - y * (y + 1);
        const long off = (long)z * (2048L * 2048);
        gemm128_body<f16, false>(QKh + off, QKh + 1024 + off, Sc + off,
                                 2048, 2048, 2048, 0, 1024, 0.03125f,
                                 y * 128, x * 64);
    }
}

// PV, uniform split-K: O = P V. Each (z, x, by) output tile (Keff = by*128+128)
// is split into ceil(Keff/512) K-chunks of <=512; every chunk is a near-equal
// block (2560 total, ~10/CU) accumulating its f32 partial into out via
// device-scope atomicAdd. This replaces LPT: no 1:16 work spread, fine-grained
// backfill, no tail. Decode reverses q so the 512-K chunks dispatch first.
// chunks/by: by 0-3 ->1, 4-7 ->2, 8-11 ->3, 12-15 ->4; cum per (z,x) = 40.
__global__ void __launch_bounds__(256)
gemm_pv(const f16* __restrict__ Sc, const f16* __restrict__ Vt,
        float* __restrict__ out)
{
    const int n = (int)blockIdx.x;       // 0..2559
    const int z = n / 640;
    const int r = n - z * 640;
    const int x = r / 40;
    const int q = 39 - (r - x * 40);     // reversed: big-by (512-K chunks) first
    int by = 0, cum = 0;
    for (;;) {
        const int nc = (by >> 2) + 1;
        if (cum + nc > q) break;
        cum += nc;
        by++;
    }
    const int c = q - cum;
    const int i0 = by * 128;
    const int j0 = x * 64;
    const int Keff = i0 + 128;
    const int kLo = c * 512;
    const int kHi = min(Keff, kLo + 512);
    gemm128_body<float, true>(Sc + (long)z * (2048L * 2048),
                              Vt + (long)z * 2048,
                              out + (long)z * (2048L * 1024),
                              2048, 8192, 1024, kLo, kHi, 1.f, i0, j0);
}

// in-place causal softmax over fp16 scores; one block per row, 256 thr x 8 cols.
// Only the live prefix L = ((i>>7)+1)*128 is read/written.
__global__ void __launch_bounds__(256)
softmax_causal(f16* __restrict__ Sc)
{
    const int S = 2048;
    const long rowg = blockIdx.x;
    const long b = rowg >> 11;
    const int  i = (int)(rowg & 2047);
    f16* row = Sc + ((b * S + i) * (long)S);
    const int L = ((i >> 7) + 1) << 7;   // tile-aligned live row length

    const int tid = threadIdx.x;
    const int c0  = tid * 8;
    const int lane = tid & 63, wave = tid >> 6;
    const bool act = c0 < L;

    float v[8];
    float m = -3.4e38f;
    if (act) {
        f16x8 in = *(const f16x8*)(row + c0);
        #pragma unroll
        for (int j = 0; j < 8; j++) {
            const bool ok = (c0 + j) <= i;
            v[j] = ok ? (float)in[j] : -3.4e38f;
            m = fmaxf(m, v[j]);
        }
    }
    #pragma unroll
    for (int off = 32; off > 0; off >>= 1)
        m = fmaxf(m, __shfl_down(m, off, 64));
    __shared__ float redm[4];
    if (lane == 0) redm[wave] = m;
    __syncthreads();
    const float m0 = fmaxf(fmaxf(redm[0], redm[1]), fmaxf(redm[2], redm[3]));

    float e[8];
    float s = 0.f;
    if (act) {
        #pragma unroll
        for (int j = 0; j < 8; j++) {
            const bool ok = (c0 + j) <= i;
            e[j] = ok ? __expf(v[j] - m0) : 0.f;
            s += e[j];
        }
    }
    #pragma unroll
    for (int off = 32; off > 0; off >>= 1)
        s += __shfl_down(s, off, 64);
    __shared__ float reds[4];
    if (lane == 0) reds[wave] = s;
    __syncthreads();
    const float inv = 1.f / (reds[0] + reds[1] + reds[2] + reds[3]);

    if (act) {
        f16x8 o;
        #pragma unroll
        for (int j = 0; j < 8; j++) o[j] = (f16)(e[j] * inv);
        *(f16x8*)(row + c0) = o;
    }
}

// fused fp32->fp16 of x, Wq, Wk, Wv in one dispatch.
__global__ void __launch_bounds__(256)
convert_all(const float* __restrict__ x, const float* __restrict__ Wq,
            const float* __restrict__ Wk, const float* __restrict__ Wv,
            f16* __restrict__ xh, f16* __restrict__ wh)
{
    const long blk = blockIdx.x;
    const float* src;
    f16* dst;
    long base;
    if (blk < 4096)      { src = x;  dst = xh;                    base = blk * 2048; }
    else if (blk < 4608) { src = Wq; dst = wh;                    base = (blk - 4096) * 2048; }
    else if (blk < 5120) { src = Wk; dst = wh + 1024L * 1024;     base = (blk - 4608) * 2048; }
    else                 { src = Wv; dst = wh + 2L * 1024 * 1024; base = (blk - 5120) * 2048; }
    const long i = base + (long)threadIdx.x * 8;
    f32x4 a = *(const f32x4*)(src + i);
    f32x4 b = *(const f32x4*)(src + i + 4);
    f16x8 o;
    o[0] = (f16)a[0]; o[1] = (f16)a[1]; o[2] = (f16)a[2]; o[3] = (f16)a[3];
    o[4] = (f16)b[0]; o[5] = (f16)b[1]; o[6] = (f16)b[2]; o[7] = (f16)b[3];
    *(f16x8*)(dst + i) = o;
}

extern "C" void kernel_launch(void* const* d_in, const int* in_sizes, int n_in,
                              void* d_out, int out_size, void* d_ws, size_t ws_size,
                              hipStream_t stream)
{
    (void)in_sizes; (void)n_in; (void)out_size; (void)ws_size;
    const float* x  = (const float*)d_in[0];
    const float* Wq = (const float*)d_in[1];
    const float* Wk = (const float*)d_in[2];
    const float* Wv = (const float*)d_in[3];
    float* out = (float*)d_out;

    const long NX = 4L * 2048 * 1024;   // B*S*E = 8388608
    const long NW = 1024L * 1024;

    char* p = (char*)d_ws;
    f16* xh  = (f16*)p; p += NX * 2;
    f16* wh  = (f16*)p; p += 3 * NW * 2;            // Wq | Wk | Wv contiguous
    f16* QKh = (f16*)p; p += 2 * NX * 2;            // [8192][2048]: Q cols | K cols
    f16* Vt  = (f16*)p; p += NX * 2;                // [E=1024][B*S=8192]
    f16* Sc  = (f16*)p; p += 4L * 2048 * 2048 * 2;  // scores -> P in place
    f16* wvh = wh + 2L * NW;

    convert_all<<<5632, 256, 0, stream>>>(x, Wq, Wk, Wv, xh, wh);

    // QK = x [Wq;Wk]^T : [8192,2048] via 8-phase 256^2, XCD-chunk swizzled
    gemm256_k1024<<<256, 512, 0, stream>>>(
        xh, wh, QKh, 1024, 1024, 2048);

    // merged: V^T (1024 blocks) + Sc lower-tri (1088 blocks), XCD-chunked
    gemm_vt_sc<<<2112, 256, 0, stream>>>(xh, wvh, QKh, Vt, Sc);

    // causal softmax in place (live prefix only)
    softmax_causal<<<4 * 2048, 256, 0, stream>>>(Sc);

    // O = P V, uniform split-K (<=512-K chunks) with f32 atomic accumulate
    gemm_pv<<<2560, 256, 0, stream>>>(Sc, Vt, out);
}

// Round 9
// 219.594 us; speedup vs baseline: 1.1237x; 1.1237x over previous
//
#include <hip/hip_runtime.h>

typedef _Float16 f16;
typedef _Float16 f16x8 __attribute__((ext_vector_type(8)));
typedef float    f32x4 __attribute__((ext_vector_type(4)));

// async global->LDS, 16B per lane; LDS dest = wave-uniform base + lane*16.
// Global source address is per-lane arbitrary (we exploit this for swizzling).
__device__ __forceinline__ void gld_lds16(const void* g, void* l) {
    __builtin_amdgcn_global_load_lds((__attribute__((address_space(1))) void*)g,
                                     (__attribute__((address_space(3))) void*)l,
                                     16, 0, 0);
}

// compiler-barrier-wrapped s_barrier: LDS/global ops must not migrate across.
#define BARRIER() do { asm volatile("" ::: "memory"); \
                       __builtin_amdgcn_s_barrier();  \
                       asm volatile("" ::: "memory"); } while (0)

// ---------------------------------------------------------------------------
// 8-phase 256x256xBK64 GEMM (C = A * B^T, f16 out), K = 1024 (16 K-tiles).
// 512 thr = 8 waves (2Mx4N); per-wave 128x64 output = acc[8][4] 16x16 frags.
// LDS: 2 buffers x (A 256x64 + B 256x64) f16 = 128 KiB, XOR-chunk swizzled.
// Per K-tile t (reads buf[t&1]; stages tile t+1 into buf[(t+1)&1]). 4 phases,
// 16 MFMA each; fragment reads are per-phase (peak ~10 live frags, no spill).
// vmcnt(2) at end-ph1/ph4 only: loads never drain to 0 in the main loop.
// ---------------------------------------------------------------------------
template<bool STG, int VM1, int VM4>
__device__ __forceinline__ void tile256(
    f32x4 (&acc)[8][4],
    const f16* Ak0, const f16* Ak1, const f16* Bk0, const f16* Bk1,
    const f16* gAn, const f16* gBn,   // next-tile global bases (k-adjusted)
    f16* lAn, f16* lBn,               // next-tile LDS dests (other buffer)
    int lda, int ldb)
{
    // ---- phase 1: kk0, m-frags 0-3 ----
    {
        f16x8 a[4], b[4];
        #pragma unroll
        for (int mf = 0; mf < 4; mf++) a[mf] = *(const f16x8*)(Ak0 + mf * 1024);
        #pragma unroll
        for (int nf = 0; nf < 4; nf++) b[nf] = *(const f16x8*)(Bk0 + nf * 1024);
        if (STG) {
            gld_lds16(gBn,                  lBn);
            gld_lds16(gBn + (long)64 * ldb, lBn + 4096);
        }
        BARRIER();
        __builtin_amdgcn_s_setprio(1);
        #pragma unroll
        for (int mf = 0; mf < 4; mf++)
            #pragma unroll
            for (int nf = 0; nf < 4; nf++)
                acc[mf][nf] = __builtin_amdgcn_mfma_f32_16x16x32_f16(
                    a[mf], b[nf], acc[mf][nf], 0, 0, 0);
        __builtin_amdgcn_s_setprio(0);
        if (VM1 == 2)      asm volatile("s_waitcnt vmcnt(2)" ::: "memory");
        else if (VM1 == 0) asm volatile("s_waitcnt vmcnt(0)" ::: "memory");
        BARRIER();
        // ---- phase 2: kk0, m-frags 4-7 (b still live) ----
        f16x8 a2[4];
        #pragma unroll
        for (int mf = 0; mf < 4; mf++) a2[mf] = *(const f16x8*)(Ak0 + (mf + 4) * 1024);
        if (STG) {
            gld_lds16(gBn + (long)128 * ldb, lBn + 8192);
            gld_lds16(gBn + (long)192 * ldb, lBn + 12288);
        }
        BARRIER();
        __builtin_amdgcn_s_setprio(1);
        #pragma unroll
        for (int mf = 0; mf < 4; mf++)
            #pragma unroll
            for (int nf = 0; nf < 4; nf++)
                acc[mf + 4][nf] = __builtin_amdgcn_mfma_f32_16x16x32_f16(
                    a2[mf], b[nf], acc[mf + 4][nf], 0, 0, 0);
        __builtin_amdgcn_s_setprio(0);
        BARRIER();
    }
    // ---- phase 3: kk1, m-frags 0-3 ----
    {
        f16x8 a[4], b[4];
        #pragma unroll
        for (int mf = 0; mf < 4; mf++) a[mf] = *(const f16x8*)(Ak1 + mf * 1024);
        #pragma unroll
        for (int nf = 0; nf < 4; nf++) b[nf] = *(const f16x8*)(Bk1 + nf * 1024);
        if (STG) {
            gld_lds16(gAn,                   lAn);
            gld_lds16(gAn + (long)128 * lda, lAn + 8192);
        }
        BARRIER();
        __builtin_amdgcn_s_setprio(1);
        #pragma unroll
        for (int mf = 0; mf < 4; mf++)
            #pragma unroll
            for (int nf = 0; nf < 4; nf++)
                acc[mf][nf] = __builtin_amdgcn_mfma_f32_16x16x32_f16(
                    a[mf], b[nf], acc[mf][nf], 0, 0, 0);
        __builtin_amdgcn_s_setprio(0);
        BARRIER();
        // ---- phase 4: kk1, m-frags 4-7 ----
        f16x8 a2[4];
        #pragma unroll
        for (int mf = 0; mf < 4; mf++) a2[mf] = *(const f16x8*)(Ak1 + (mf + 4) * 1024);
        if (STG) {
            gld_lds16(gAn + (long)64 * lda,  lAn + 4096);
            gld_lds16(gAn + (long)192 * lda, lAn + 12288);
        }
        BARRIER();
        __builtin_amdgcn_s_setprio(1);
        #pragma unroll
        for (int mf = 0; mf < 4; mf++)
            #pragma unroll
            for (int nf = 0; nf < 4; nf++)
                acc[mf + 4][nf] = __builtin_amdgcn_mfma_f32_16x16x32_f16(
                    a2[mf], b[nf], acc[mf + 4][nf], 0, 0, 0);
        __builtin_amdgcn_s_setprio(0);
        if (VM4 == 2)      asm volatile("s_waitcnt vmcnt(2)" ::: "memory");
        else if (VM4 == 0) asm volatile("s_waitcnt vmcnt(0)" ::: "memory");
        BARRIER();
    }
}

// grid = 256 1-D blocks. XCD-chunk swizzle (T1): XCD k gets 32 consecutive
// logical tiles = 4 i-tiles x all 8 j-tiles, so the full B operand (4 MB)
// exactly fits that XCD's L2 and A-panels are fetched once per XCD.
__global__ void __launch_bounds__(512, 2)
gemm256_k1024(const f16* __restrict__ A, const f16* __restrict__ B,
              f16* __restrict__ C, int lda, int ldb, int ldc)
{
    const int m  = (int)blockIdx.x;            // 0..255
    const int L  = (m & 7) * 32 + (m >> 3);    // bijective: 256 = 8*32
    const int i0 = (L >> 3) * 256;             // 32 i-tiles
    const int j0 = (L & 7) * 256;              // 8 j-tiles

    __shared__ f16 Lds[2 * 32768] __attribute__((aligned(16)));

    const int tid  = threadIdx.x;
    const int lane = tid & 63;
    const int wave = tid >> 6;
    const int wm = wave >> 2, wn = wave & 3;
    const int row16 = lane & 15, quad = lane >> 4;
    const int swz = row16 & 7;

    // per-thread LDS read bases (buf0; buf1 = +32768). chunk XOR-deswizzle:
    // LDS[row][cb] holds global chunk cb^(row&7) -> read chunk (k-chunk ^ swz).
    const int c0 = (quad ^ swz) * 8;           // kk0 chunk
    const int c1 = ((quad + 4) ^ swz) * 8;     // kk1 chunk
    const f16* A0k0 = Lds + (wm * 128 + row16) * 64 + c0;
    const f16* A0k1 = Lds + (wm * 128 + row16) * 64 + c1;
    const f16* B0k0 = Lds + 16384 + (wn * 64 + row16) * 64 + c0;
    const f16* B0k1 = Lds + 16384 + (wn * 64 + row16) * 64 + c1;

    // staging: 512 thr x 16B cover one 64-row quarter (64x64 f16) per issue.
    const int srow = tid >> 3;                       // 0..63
    const int scol = ((tid & 7) ^ (srow & 7)) * 8;   // swizzled global col
    const f16* gA = A + (long)(i0 + srow) * lda + scol;
    const f16* gB = B + (long)(j0 + srow) * ldb + scol;
    f16* lA0 = Lds + tid * 8;
    f16* lB0 = Lds + 16384 + tid * 8;
    f16* lA1 = Lds + 32768 + tid * 8;
    f16* lB1 = Lds + 32768 + 16384 + tid * 8;

    // prologue: tile 0 -> buf0, issue order = steady staging order:
    // Bq0,Bq1,Bq2,Bq3,Aq0,Aq2,Aq1,Aq3; vmcnt(2) keeps Aq1,Aq3 in flight.
    gld_lds16(gB,                   lB0);
    gld_lds16(gB + (long)64 * ldb,  lB0 + 4096);
    gld_lds16(gB + (long)128 * ldb, lB0 + 8192);
    gld_lds16(gB + (long)192 * ldb, lB0 + 12288);
    gld_lds16(gA,                   lA0);
    gld_lds16(gA + (long)128 * lda, lA0 + 8192);
    gld_lds16(gA + (long)64 * lda,  lA0 + 4096);
    gld_lds16(gA + (long)192 * lda, lA0 + 12288);

    f32x4 acc[8][4] = {};

    asm volatile("s_waitcnt vmcnt(2)" ::: "memory");
    BARRIER();

    // 16 K-tiles: 7 steady pairs (tiles 0-13) + tile 14 (last stage) + tile 15
    for (int t = 0; t < 14; t += 2) {
        tile256<true, 2, 2>(acc, A0k0, A0k1, B0k0, B0k1,
                            gA + (t + 1) * 64, gB + (t + 1) * 64,
                            lA1, lB1, lda, ldb);
        tile256<true, 2, 2>(acc, A0k0 + 32768, A0k1 + 32768,
                            B0k0 + 32768, B0k1 + 32768,
                            gA + (t + 2) * 64, gB + (t + 2) * 64,
                            lA0, lB0, lda, ldb);
    }
    tile256<true, 2, 2>(acc, A0k0, A0k1, B0k0, B0k1,
                        gA + 15 * 64, gB + 15 * 64, lA1, lB1, lda, ldb);
    tile256<false, 0, -1>(acc, A0k0 + 32768, A0k1 + 32768,
                          B0k0 + 32768, B0k1 + 32768,
                          nullptr, nullptr, nullptr, nullptr, lda, ldb);

    // epilogue: C[row][col], col = lane&15, row = quad*4 + reg
    #pragma unroll
    for (int mf = 0; mf < 8; mf++) {
        const int r0 = i0 + wm * 128 + mf * 16 + quad * 4;
        #pragma unroll
        for (int nf = 0; nf < 4; nf++) {
            const int c = j0 + wn * 64 + nf * 16 + row16;
            #pragma unroll
            for (int r = 0; r < 4; r++)
                C[(long)(r0 + r) * ldc + c] = (f16)acc[mf][nf][r];
        }
    }
}

// ---------------------------------------------------------------------------
// 128x64x64 GEMM body, shared by the merged Vt+scores kernel and PV.
// 4 waves 2x2, each wave 64x32 out (acc[4][2]); ~48 VGPR / 24KB LDS -> 6+
// blocks/CU; cross-block overlap hides the 2-barrier drain stall.
// (Split-K + atomicAdd epilogue was tried in r8 and regressed 1.7x:
//  WRITE_SIZE 33->82MB, 21M device-scope atomics, MfmaUtil 9%. Plain stores.)
// ---------------------------------------------------------------------------
template<typename OutT>
__device__ __forceinline__ void gemm128_body(
    const f16* __restrict__ A, const f16* __restrict__ B, OutT* __restrict__ C,
    int lda, int ldb, int ldc, int Keff, float scale, int i0, int j0)
{
    __shared__ f16 As[128 * 64] __attribute__((aligned(16)));
    __shared__ f16 Bs[64 * 64]  __attribute__((aligned(16)));

    const int tid  = threadIdx.x;
    const int lane = tid & 63;
    const int wave = tid >> 6;
    const int row16 = lane & 15;
    const int quad  = lane >> 4;
    const int swz   = row16 & 7;
    const int wr = (wave >> 1) * 64;   // wave row offset: 0 / 64
    const int wc = (wave & 1) * 32;    // wave col offset: 0 / 32

    const int srow = tid >> 3;                       // 0..31
    const int scol = ((tid & 7) ^ (srow & 7)) * 8;   // swizzled global col
    const f16* gA = A + (long)(i0 + srow) * lda + scol;
    const f16* gB = B + (long)(j0 + srow) * ldb + scol;
    f16* lA = As + tid * 8;   // + p*32*64
    f16* lB = Bs + tid * 8;

    f32x4 acc[4][2] = {};

    for (int k0 = 0; k0 < Keff; k0 += 64) {
        gld_lds16(gA + k0,                  lA);
        gld_lds16(gA + k0 + (long)32 * lda, lA + 32 * 64);
        gld_lds16(gA + k0 + (long)64 * lda, lA + 64 * 64);
        gld_lds16(gA + k0 + (long)96 * lda, lA + 96 * 64);
        gld_lds16(gB + k0,                  lB);
        gld_lds16(gB + k0 + (long)32 * ldb, lB + 32 * 64);
        __syncthreads();

        #pragma unroll
        for (int kk = 0; kk < 2; kk++) {
            f16x8 af[4], bf[2];
            #pragma unroll
            for (int t = 0; t < 4; t++)
                af[t] = *(const f16x8*)(As + (wr + t * 16 + row16) * 64
                                           + (((kk * 4 + quad) ^ swz) * 8));
            #pragma unroll
            for (int t = 0; t < 2; t++)
                bf[t] = *(const f16x8*)(Bs + (wc + t * 16 + row16) * 64
                                           + (((kk * 4 + quad) ^ swz) * 8));
            #pragma unroll
            for (int mt = 0; mt < 4; mt++)
                #pragma unroll
                for (int nt = 0; nt < 2; nt++)
                    acc[mt][nt] = __builtin_amdgcn_mfma_f32_16x16x32_f16(
                        af[mt], bf[nt], acc[mt][nt], 0, 0, 0);
        }
        __syncthreads();
    }

    // epilogue: C[row][col], col = lane&15, row = quad*4 + reg
    #pragma unroll
    for (int mt = 0; mt < 4; mt++) {
        const int r0 = i0 + wr + mt * 16 + quad * 4;
        #pragma unroll
        for (int nt = 0; nt < 2; nt++) {
            const int c = j0 + wc + nt * 16 + row16;
            #pragma unroll
            for (int r = 0; r < 4; r++)
                C[(long)(r0 + r) * ldc + c] = (OutT)(acc[mt][nt][r] * scale);
        }
    }
}

// Merged V^T + scores dispatch: 2112 uniform-work blocks (K=1024), with
// XCD-chunk swizzles (T1) so panel-sharing blocks land on one XCD's L2:
//  blocks [0,1024): V^T = Wv x^T. Logical order i-inner/j-outer (L = j*8+i);
//    chunk 128 logical tiles per XCD -> each xh B-panel (128KB, shared by the
//    8 i-blocks) is consumed within one XCD; wvh (2MB) is L2-resident.
//  blocks [1024,2112): Sc = Q K^T / 32, lower-tri 64-wide tiles (272/batch,
//    row-band-major); chunk 136 per XCD -> Q-panels fetched once per XCD.
// Measured at the 128-engine structural floor (49.3 us, FETCH 47MB, r7).
__global__ void __launch_bounds__(256)
gemm_vt_sc(const f16* __restrict__ xh, const f16* __restrict__ wvh,
           const f16* __restrict__ QKh, f16* __restrict__ Vt,
           f16* __restrict__ Sc)
{
    const int blk = (int)blockIdx.x;
    if (blk < 1024) {
        const int L = (blk & 7) * 128 + (blk >> 3);   // bijective: 1024 = 8*128
        const int j = L >> 3;                          // 0..127 (col tile)
        const int i = L & 7;                           // 0..7   (row tile)
        gemm128_body<f16>(wvh, xh, Vt, 1024, 1024, 8192, 1024, 1.f,
                          i * 128, j * 64);
    } else {
        const int m = blk - 1024;                      // 0..1087
        const int L = (m & 7) * 136 + (m >> 3);        // bijective: 1088 = 8*136
        const int z = L / 272;                         // batch
        const int r = L - z * 272;
        int y = 0;
        while ((y + 1) * (y + 2) <= r) y++;            // cum(y) = y(y+1); r <= 271
        const int x = r - y * (y + 1);
        const long off = (long)z * (2048L * 2048);
        gemm128_body<f16>(QKh + off, QKh + 1024 + off, Sc + off,
                          2048, 2048, 2048, 1024, 0.03125f, y * 128, x * 64);
    }
}

// PV: O = P V. A = P [2048,2048] (f16, batch z), B = Vt [1024][8192] with
// batch z's tokens at columns z*2048 (B base = Vt + z*2048, ldb=8192).
// Keff = i0+128 (P rows zero beyond the diagonal tile).
// GLOBAL LPT: 1-D grid of 1024; decode d=n>>6 -> by=15-d (strictly descending
// Keff machine-wide), rem=n&63 -> x=rem>>2, z=rem&3. All 64 largest blocks
// (16 K-tile units each) dispatch first; by=0 (1 unit) backfills the tail.
// Work = 8704 units / 256 CU = 34 units/CU; makespan ~36 units ~= 27 us.
__global__ void __launch_bounds__(256)
gemm_pv(const f16* __restrict__ Sc, const f16* __restrict__ Vt,
        float* __restrict__ out)
{
    const int n  = (int)blockIdx.x;      // 0..1023
    const int by = 15 - (n >> 6);        // descending Keff
    const int rem = n & 63;
    const int x  = rem >> 2;             // 0..15
    const int z  = rem & 3;              // 0..3
    const int i0 = by * 128;
    const int j0 = x * 64;
    const int Keff = i0 + 128;
    gemm128_body<float>(Sc + (long)z * (2048L * 2048),
                        Vt + (long)z * 2048,
                        out + (long)z * (2048L * 1024),
                        2048, 8192, 1024, Keff, 1.f, i0, j0);
}

// in-place causal softmax over fp16 scores; one block per row, 256 thr x 8 cols.
// Only the live prefix L = ((i>>7)+1)*128 is read/written.
__global__ void __launch_bounds__(256)
softmax_causal(f16* __restrict__ Sc)
{
    const int S = 2048;
    const long rowg = blockIdx.x;
    const long b = rowg >> 11;
    const int  i = (int)(rowg & 2047);
    f16* row = Sc + ((b * S + i) * (long)S);
    const int L = ((i >> 7) + 1) << 7;   // tile-aligned live row length

    const int tid = threadIdx.x;
    const int c0  = tid * 8;
    const int lane = tid & 63, wave = tid >> 6;
    const bool act = c0 < L;

    float v[8];
    float m = -3.4e38f;
    if (act) {
        f16x8 in = *(const f16x8*)(row + c0);
        #pragma unroll
        for (int j = 0; j < 8; j++) {
            const bool ok = (c0 + j) <= i;
            v[j] = ok ? (float)in[j] : -3.4e38f;
            m = fmaxf(m, v[j]);
        }
    }
    #pragma unroll
    for (int off = 32; off > 0; off >>= 1)
        m = fmaxf(m, __shfl_down(m, off, 64));
    __shared__ float redm[4];
    if (lane == 0) redm[wave] = m;
    __syncthreads();
    const float m0 = fmaxf(fmaxf(redm[0], redm[1]), fmaxf(redm[2], redm[3]));

    float e[8];
    float s = 0.f;
    if (act) {
        #pragma unroll
        for (int j = 0; j < 8; j++) {
            const bool ok = (c0 + j) <= i;
            e[j] = ok ? __expf(v[j] - m0) : 0.f;
            s += e[j];
        }
    }
    #pragma unroll
    for (int off = 32; off > 0; off >>= 1)
        s += __shfl_down(s, off, 64);
    __shared__ float reds[4];
    if (lane == 0) reds[wave] = s;
    __syncthreads();
    const float inv = 1.f / (reds[0] + reds[1] + reds[2] + reds[3]);

    if (act) {
        f16x8 o;
        #pragma unroll
        for (int j = 0; j < 8; j++) o[j] = (f16)(e[j] * inv);
        *(f16x8*)(row + c0) = o;
    }
}

// fused fp32->fp16 of x, Wq, Wk, Wv in one dispatch.
__global__ void __launch_bounds__(256)
convert_all(const float* __restrict__ x, const float* __restrict__ Wq,
            const float* __restrict__ Wk, const float* __restrict__ Wv,
            f16* __restrict__ xh, f16* __restrict__ wh)
{
    const long blk = blockIdx.x;
    const float* src;
    f16* dst;
    long base;
    if (blk < 4096)      { src = x;  dst = xh;                    base = blk * 2048; }
    else if (blk < 4608) { src = Wq; dst = wh;                    base = (blk - 4096) * 2048; }
    else if (blk < 5120) { src = Wk; dst = wh + 1024L * 1024;     base = (blk - 4608) * 2048; }
    else                 { src = Wv; dst = wh + 2L * 1024 * 1024; base = (blk - 5120) * 2048; }
    const long i = base + (long)threadIdx.x * 8;
    f32x4 a = *(const f32x4*)(src + i);
    f32x4 b = *(const f32x4*)(src + i + 4);
    f16x8 o;
    o[0] = (f16)a[0]; o[1] = (f16)a[1]; o[2] = (f16)a[2]; o[3] = (f16)a[3];
    o[4] = (f16)b[0]; o[5] = (f16)b[1]; o[6] = (f16)b[2]; o[7] = (f16)b[3];
    *(f16x8*)(dst + i) = o;
}

extern "C" void kernel_launch(void* const* d_in, const int* in_sizes, int n_in,
                              void* d_out, int out_size, void* d_ws, size_t ws_size,
                              hipStream_t stream)
{
    (void)in_sizes; (void)n_in; (void)out_size; (void)ws_size;
    const float* x  = (const float*)d_in[0];
    const float* Wq = (const float*)d_in[1];
    const float* Wk = (const float*)d_in[2];
    const float* Wv = (const float*)d_in[3];
    float* out = (float*)d_out;

    const long NX = 4L * 2048 * 1024;   // B*S*E = 8388608
    const long NW = 1024L * 1024;

    char* p = (char*)d_ws;
    f16* xh  = (f16*)p; p += NX * 2;
    f16* wh  = (f16*)p; p += 3 * NW * 2;            // Wq | Wk | Wv contiguous
    f16* QKh = (f16*)p; p += 2 * NX * 2;            // [8192][2048]: Q cols | K cols
    f16* Vt  = (f16*)p; p += NX * 2;                // [E=1024][B*S=8192]
    f16* Sc  = (f16*)p; p += 4L * 2048 * 2048 * 2;  // scores -> P in place
    f16* wvh = wh + 2L * NW;

    convert_all<<<5632, 256, 0, stream>>>(x, Wq, Wk, Wv, xh, wh);

    // QK = x [Wq;Wk]^T : [8192,2048] via 8-phase 256^2, XCD-chunk swizzled
    gemm256_k1024<<<256, 512, 0, stream>>>(
        xh, wh, QKh, 1024, 1024, 2048);

    // merged: V^T (1024 blocks) + Sc lower-tri (1088 blocks), XCD-chunked
    gemm_vt_sc<<<2112, 256, 0, stream>>>(xh, wvh, QKh, Vt, Sc);

    // causal softmax in place (live prefix only)
    softmax_causal<<<4 * 2048, 256, 0, stream>>>(Sc);

    // O = P V, global-LPT ordered (all largest-Keff blocks dispatch first)
    gemm_pv<<<1024, 256, 0, stream>>>(Sc, Vt, out);
}